// Round 1
// baseline (594.619 us; speedup 1.0000x reference)
//
#include <hip/hip_runtime.h>
#include <hip/hip_bf16.h>

#define DM 256
#define NH 8
#define HD 32
#define NLV 3
#define NPT 4
#define NLP 12
#define BB 16
#define LQ 300
#define NT 8400
#define MROWS (BB * NT)      // 134400
#define QROWS (BB * LQ)      // 4800

// ---------------------------------------------------------------------------
// Kernel 1: value = input_flatten @ W_val + b_val, permuted to (b, h, n, d),
// stored bf16.  BM=64, BN=256(full), K-tile 32. 8x8 register blocking.
// ---------------------------------------------------------------------------
__global__ __launch_bounds__(256) void k_valproj(
    const float* __restrict__ A,      // (134400, 256)
    const float* __restrict__ W,      // (256, 256)
    const float* __restrict__ bias,   // (256,)
    __hip_bfloat16* __restrict__ V)   // (16, 8, 8400, 32)
{
    __shared__ float As[64 * 33];
    __shared__ float Ws[32 * 256];
    const int t   = threadIdx.x;
    const int m0  = blockIdx.x * 64;
    const int tn  = (t & 31) * 8;     // output col base (0..248)
    const int tmg = (t >> 5) * 8;     // output row base within tile (0..56)

    float acc[8][8];
#pragma unroll
    for (int i = 0; i < 8; i++)
#pragma unroll
        for (int j = 0; j < 8; j++) acc[i][j] = 0.f;

    for (int kt = 0; kt < 256; kt += 32) {
        // stage A tile 64x32 (pad row stride 33)
#pragma unroll
        for (int i = 0; i < 2; i++) {
            int f  = t + i * 256;
            int r  = f >> 3;
            int kq = (f & 7) * 4;
            float4 a4 = *(const float4*)(A + (size_t)(m0 + r) * 256 + kt + kq);
            float* dst = &As[r * 33 + kq];
            dst[0] = a4.x; dst[1] = a4.y; dst[2] = a4.z; dst[3] = a4.w;
        }
        // stage W tile 32x256
#pragma unroll
        for (int i = 0; i < 8; i++) {
            int f  = t + i * 256;
            int kr = f >> 6;
            int cq = (f & 63) * 4;
            *(float4*)(&Ws[kr * 256 + cq]) =
                *(const float4*)(W + (size_t)(kt + kr) * 256 + cq);
        }
        __syncthreads();
#pragma unroll 4
        for (int k = 0; k < 32; k++) {
            float a[8], w[8];
#pragma unroll
            for (int i = 0; i < 8; i++) a[i] = As[(tmg + i) * 33 + k];
            float4 w0 = *(float4*)(&Ws[k * 256 + tn]);
            float4 w1 = *(float4*)(&Ws[k * 256 + tn + 4]);
            w[0] = w0.x; w[1] = w0.y; w[2] = w0.z; w[3] = w0.w;
            w[4] = w1.x; w[5] = w1.y; w[6] = w1.z; w[7] = w1.w;
#pragma unroll
            for (int i = 0; i < 8; i++)
#pragma unroll
                for (int j = 0; j < 8; j++)
                    acc[i][j] = fmaf(a[i], w[j], acc[i][j]);
        }
        __syncthreads();
    }

    // epilogue: add bias, convert bf16, permuted store (b, h, pos, d)
    const int h = tn >> 5;
    const int d = tn & 31;
    float bv[8];
#pragma unroll
    for (int j = 0; j < 8; j++) bv[j] = bias[tn + j];
#pragma unroll
    for (int i = 0; i < 8; i++) {
        int m   = m0 + tmg + i;
        int b   = m / NT;
        int pos = m - b * NT;
        union { __hip_bfloat162 h2[4]; float4 f4; } u;
#pragma unroll
        for (int jj = 0; jj < 4; jj++) {
            float lo = acc[i][2 * jj] + bv[2 * jj];
            float hi = acc[i][2 * jj + 1] + bv[2 * jj + 1];
            u.h2[jj] = __float22bfloat162_rn(make_float2(lo, hi));
        }
        *(float4*)(V + ((size_t)((b * NH + h) * NT + pos)) * HD + d) = u.f4;
    }
}

// ---------------------------------------------------------------------------
// Kernel 2: off_raw = query @ W_off + b_off ; attn_raw = query @ W_attn + b_attn
// BM=32 rows per block; thread t handles col t (and t+256 if < 288).
// ---------------------------------------------------------------------------
__global__ __launch_bounds__(256) void k_offattn(
    const float* __restrict__ Q,       // (4800, 256)
    const float* __restrict__ Woff,    // (256, 192)
    const float* __restrict__ boff,    // (192,)
    const float* __restrict__ Wattn,   // (256, 96)
    const float* __restrict__ battn,   // (96,)
    float* __restrict__ off_out,       // (4800, 192)
    float* __restrict__ attn_out)      // (4800, 96)
{
    __shared__ float Qs[32 * 256];
    const int t  = threadIdx.x;
    const int m0 = blockIdx.x * 32;
#pragma unroll
    for (int i = 0; i < 8; i++) {
        int f  = t + i * 256;
        int r  = f >> 6;
        int cq = (f & 63) * 4;
        *(float4*)(&Qs[r * 256 + cq]) =
            *(const float4*)(Q + (size_t)(m0 + r) * 256 + cq);
    }
    __syncthreads();

    for (int pass = 0; pass < 2; pass++) {
        int c = t + (pass << 8);
        if (c >= 288) break;
        float acc[32];
#pragma unroll
        for (int r = 0; r < 32; r++) acc[r] = 0.f;
        const bool isoff = (c < 192);
        const float* Wp  = isoff ? (Woff + c) : (Wattn + (c - 192));
        const int stride = isoff ? 192 : 96;
        for (int k = 0; k < 256; k += 4) {
            float w0 = Wp[(k + 0) * stride];
            float w1 = Wp[(k + 1) * stride];
            float w2 = Wp[(k + 2) * stride];
            float w3 = Wp[(k + 3) * stride];
#pragma unroll
            for (int r = 0; r < 32; r++) {
                float4 qv = *(float4*)(&Qs[r * 256 + k]);
                acc[r] = fmaf(qv.x, w0,
                         fmaf(qv.y, w1,
                         fmaf(qv.z, w2,
                         fmaf(qv.w, w3, acc[r]))));
            }
        }
        float bias_ = isoff ? boff[c] : battn[c - 192];
        if (isoff) {
#pragma unroll
            for (int r = 0; r < 32; r++)
                off_out[(size_t)(m0 + r) * 192 + c] = acc[r] + bias_;
        } else {
            int ca = c - 192;
#pragma unroll
            for (int r = 0; r < 32; r++)
                attn_out[(size_t)(m0 + r) * 96 + ca] = acc[r] + bias_;
        }
    }
}

// ---------------------------------------------------------------------------
// Kernel 3: softmax(attn) + sampling-location compute + bilinear gather +
// weighted sum.  One block per (b, q); thread = (head h = t>>5, channel d = t&31).
// ---------------------------------------------------------------------------
__global__ __launch_bounds__(256) void k_sample(
    const float* __restrict__ off_raw,   // (4800, 192)  (h,l,p,2)
    const float* __restrict__ attn_raw,  // (4800, 96)   (h, l*4+p)
    const float* __restrict__ refp,      // (16, 300, 3, 2)
    const __hip_bfloat16* __restrict__ V,// (16, 8, 8400, 32)
    float* __restrict__ sampled)         // (4800, 256)
{
    const int t  = threadIdx.x;
    const int bq = blockIdx.x;
    const int b  = bq / LQ;

    __shared__ float aw[96];   // softmaxed attention (h, l*4+p)
    __shared__ float sx[96];   // pixel-space x per (h, l, p)
    __shared__ float sy[96];

    const float dims[3] = {80.f, 40.f, 20.f};  // square levels: W == H

    if (t < 96) {
        int h = t / 12, lp = t - h * 12, l = lp >> 2, p = lp & 3;
        float ox = off_raw[(size_t)bq * 192 + ((h * 3 + l) * 4 + p) * 2 + 0];
        float oy = off_raw[(size_t)bq * 192 + ((h * 3 + l) * 4 + p) * 2 + 1];
        float rx = refp[(size_t)bq * 6 + l * 2 + 0];
        float ry = refp[(size_t)bq * 6 + l * 2 + 1];
        float D  = dims[l];
        float lx = rx + ox / D;
        float ly = ry + oy / D;
        sx[t] = lx * D - 0.5f;
        sy[t] = ly * D - 0.5f;
    }
    if (t < 8) {
        float v[12];
        float mx = -1e30f;
#pragma unroll
        for (int i = 0; i < 12; i++) {
            v[i] = attn_raw[(size_t)bq * 96 + t * 12 + i];
            mx = fmaxf(mx, v[i]);
        }
        float s = 0.f;
#pragma unroll
        for (int i = 0; i < 12; i++) { v[i] = expf(v[i] - mx); s += v[i]; }
        float inv = 1.f / s;
#pragma unroll
        for (int i = 0; i < 12; i++) aw[t * 12 + i] = v[i] * inv;
    }
    __syncthreads();

    const int h = t >> 5, d = t & 31;
    const __hip_bfloat16* vb = V + (size_t)(b * NH + h) * NT * HD + d;

    const int   starts[3] = {0, 6400, 8000};
    const int   idim[3]   = {80, 40, 20};

    float acc = 0.f;
#pragma unroll
    for (int l = 0; l < 3; l++) {
        const int Dl = idim[l];
        const int st = starts[l];
#pragma unroll
        for (int p = 0; p < 4; p++) {
            const int s = h * 12 + l * 4 + p;
            float ix = sx[s], iy = sy[s];
            float w  = aw[s];
            float fix = floorf(ix), fiy = floorf(iy);
            int ix0 = (int)fix, iy0 = (int)fiy;
            int ix1 = ix0 + 1, iy1 = iy0 + 1;
            float fx = ix - fix, fy = iy - fiy;

            float mx0 = (ix0 >= 0 && ix0 < Dl) ? 1.f : 0.f;
            float mx1 = (ix1 >= 0 && ix1 < Dl) ? 1.f : 0.f;
            float my0 = (iy0 >= 0 && iy0 < Dl) ? 1.f : 0.f;
            float my1 = (iy1 >= 0 && iy1 < Dl) ? 1.f : 0.f;

            int cx0 = min(max(ix0, 0), Dl - 1);
            int cx1 = min(max(ix1, 0), Dl - 1);
            int cy0 = min(max(iy0, 0), Dl - 1);
            int cy1 = min(max(iy1, 0), Dl - 1);

            float v00 = mx0 * my0 * __bfloat162float(vb[(size_t)(st + cy0 * Dl + cx0) * HD]);
            float v01 = mx1 * my0 * __bfloat162float(vb[(size_t)(st + cy0 * Dl + cx1) * HD]);
            float v10 = mx0 * my1 * __bfloat162float(vb[(size_t)(st + cy1 * Dl + cx0) * HD]);
            float v11 = mx1 * my1 * __bfloat162float(vb[(size_t)(st + cy1 * Dl + cx1) * HD]);

            float sval = (1.f - fx) * (1.f - fy) * v00 + fx * (1.f - fy) * v01
                       + (1.f - fx) * fy * v10 + fx * fy * v11;
            acc = fmaf(w, sval, acc);
        }
    }
    sampled[(size_t)bq * 256 + t] = acc;
}

// ---------------------------------------------------------------------------
// Kernel 4: out = sampled @ W_out + b_out.  BM=32, BN=256, 4x8 blocking.
// ---------------------------------------------------------------------------
__global__ __launch_bounds__(256) void k_outproj(
    const float* __restrict__ A,      // (4800, 256)
    const float* __restrict__ W,      // (256, 256)
    const float* __restrict__ bias,   // (256,)
    float* __restrict__ out)          // (4800, 256)
{
    __shared__ float As[32 * 33];
    __shared__ float Ws[32 * 256];
    const int t   = threadIdx.x;
    const int m0  = blockIdx.x * 32;
    const int tn  = (t & 31) * 8;
    const int tmg = (t >> 5) * 4;

    float acc[4][8];
#pragma unroll
    for (int i = 0; i < 4; i++)
#pragma unroll
        for (int j = 0; j < 8; j++) acc[i][j] = 0.f;

    for (int kt = 0; kt < 256; kt += 32) {
        {
            int f  = t;
            int r  = f >> 3;
            int kq = (f & 7) * 4;
            float4 a4 = *(const float4*)(A + (size_t)(m0 + r) * 256 + kt + kq);
            float* dst = &As[r * 33 + kq];
            dst[0] = a4.x; dst[1] = a4.y; dst[2] = a4.z; dst[3] = a4.w;
        }
#pragma unroll
        for (int i = 0; i < 8; i++) {
            int f  = t + i * 256;
            int kr = f >> 6;
            int cq = (f & 63) * 4;
            *(float4*)(&Ws[kr * 256 + cq]) =
                *(const float4*)(W + (size_t)(kt + kr) * 256 + cq);
        }
        __syncthreads();
#pragma unroll 4
        for (int k = 0; k < 32; k++) {
            float a[4], w[8];
#pragma unroll
            for (int i = 0; i < 4; i++) a[i] = As[(tmg + i) * 33 + k];
            float4 w0 = *(float4*)(&Ws[k * 256 + tn]);
            float4 w1 = *(float4*)(&Ws[k * 256 + tn + 4]);
            w[0] = w0.x; w[1] = w0.y; w[2] = w0.z; w[3] = w0.w;
            w[4] = w1.x; w[5] = w1.y; w[6] = w1.z; w[7] = w1.w;
#pragma unroll
            for (int i = 0; i < 4; i++)
#pragma unroll
                for (int j = 0; j < 8; j++)
                    acc[i][j] = fmaf(a[i], w[j], acc[i][j]);
        }
        __syncthreads();
    }

    float bv[8];
#pragma unroll
    for (int j = 0; j < 8; j++) bv[j] = bias[tn + j];
#pragma unroll
    for (int i = 0; i < 4; i++) {
        int m = m0 + tmg + i;
        float4 o0, o1;
        o0.x = acc[i][0] + bv[0]; o0.y = acc[i][1] + bv[1];
        o0.z = acc[i][2] + bv[2]; o0.w = acc[i][3] + bv[3];
        o1.x = acc[i][4] + bv[4]; o1.y = acc[i][5] + bv[5];
        o1.z = acc[i][6] + bv[6]; o1.w = acc[i][7] + bv[7];
        *(float4*)(out + (size_t)m * 256 + tn)     = o0;
        *(float4*)(out + (size_t)m * 256 + tn + 4) = o1;
    }
}

// ---------------------------------------------------------------------------
extern "C" void kernel_launch(void* const* d_in, const int* in_sizes, int n_in,
                              void* d_out, int out_size, void* d_ws, size_t ws_size,
                              hipStream_t stream) {
    const float* query  = (const float*)d_in[0];
    const float* refp   = (const float*)d_in[1];
    const float* inputf = (const float*)d_in[2];
    const float* W_off  = (const float*)d_in[3];
    const float* b_off  = (const float*)d_in[4];
    const float* W_attn = (const float*)d_in[5];
    const float* b_attn = (const float*)d_in[6];
    const float* W_val  = (const float*)d_in[7];
    const float* b_val  = (const float*)d_in[8];
    const float* W_out  = (const float*)d_in[9];
    const float* b_out  = (const float*)d_in[10];
    float* out = (float*)d_out;

    char* ws = (char*)d_ws;
    const size_t value_bytes = (size_t)BB * NH * NT * HD * 2;   // 68,812,800
    const size_t off_bytes   = (size_t)QROWS * 192 * 4;         //  3,686,400
    const size_t attn_bytes  = (size_t)QROWS * 96 * 4;          //  1,843,200
    __hip_bfloat16* value = (__hip_bfloat16*)ws;
    float* off_raw  = (float*)(ws + value_bytes);
    float* attn_raw = (float*)(ws + value_bytes + off_bytes);
    float* sampled  = (float*)(ws + value_bytes + off_bytes + attn_bytes);

    k_valproj<<<MROWS / 64, 256, 0, stream>>>(inputf, W_val, b_val, value);
    k_offattn<<<QROWS / 32, 256, 0, stream>>>(query, W_off, b_off, W_attn, b_attn,
                                              off_raw, attn_raw);
    k_sample<<<QROWS, 256, 0, stream>>>(off_raw, attn_raw, refp, value, sampled);
    k_outproj<<<QROWS / 32, 256, 0, stream>>>(sampled, W_out, b_out, out);
}

// Round 2
// 455.147 us; speedup vs baseline: 1.3064x; 1.3064x over previous
//
#include <hip/hip_runtime.h>
#include <hip/hip_bf16.h>

#define DM 256
#define NH 8
#define HD 32
#define NLV 3
#define NPT 4
#define NLP 12
#define BB 16
#define LQ 300
#define NT 8400
#define MROWS (BB * NT)      // 134400
#define QROWS (BB * LQ)      // 4800
#define KP 40                // padded LDS K-stride (bf16 elems), 80 B, 16-B aligned

typedef __bf16 bf16x8 __attribute__((ext_vector_type(8)));
typedef float  f32x16 __attribute__((ext_vector_type(16)));

// ---------------------------------------------------------------------------
// Kernel 0: pre-transpose + pre-tile W_val to bf16.
// Wt layout: [ktile(8)][n(256)][k(32)] bf16  -> a K-tile is 16 KB contiguous.
// ---------------------------------------------------------------------------
__global__ void k_wt(const float* __restrict__ W, __hip_bfloat16* __restrict__ Wt)
{
    const int n = blockIdx.x;      // 0..255 output col
    const int k = threadIdx.x;     // 0..255 input row
    Wt[(size_t)(k >> 5) * 8192 + n * 32 + (k & 31)] = __float2bfloat16(W[(size_t)k * 256 + n]);
}

// ---------------------------------------------------------------------------
// Kernel 1: value = input_flatten @ W_val + b_val (bf16 MFMA), permuted store
// to (b, h, pos, d) bf16.  Block: 64 rows x 256 cols, 256 thr = 4 waves,
// wave w covers n in [w*64, w*64+64), 2x2 tiles of 32x32, BK=32.
// ---------------------------------------------------------------------------
__global__ __launch_bounds__(256) void k_valproj(
    const float* __restrict__ A,             // (134400, 256) fp32
    const __hip_bfloat16* __restrict__ Wt,   // tiled bf16 W^T
    const float* __restrict__ bias,          // (256,)
    __hip_bfloat16* __restrict__ V)          // (16, 8, 8400, 32)
{
    __shared__ __hip_bfloat16 As[64 * KP];
    __shared__ __hip_bfloat16 Ws[256 * KP];

    const int t    = threadIdx.x;
    const int m0   = blockIdx.x * 64;
    const int wave = t >> 6;
    const int lane = t & 63;
    const int lm   = lane & 31;          // row/col within 32-tile
    const int lk   = (lane >> 5) * 8;    // k base within 16-step (0 or 8)

    f32x16 acc[2][2];
#pragma unroll
    for (int i = 0; i < 2; i++)
#pragma unroll
        for (int j = 0; j < 2; j++)
#pragma unroll
            for (int e = 0; e < 16; e++) acc[i][j][e] = 0.f;

    // staging indices
    const int ar = t >> 2;               // A row 0..63
    const int ak = (t & 3) * 8;          // A k-chunk 0,8,16,24

    for (int kt = 0; kt < 256; kt += 32) {
        // ---- stage A tile (64 x 32) fp32 -> bf16 ----
        {
            const float* ap = A + (size_t)(m0 + ar) * 256 + kt + ak;
            float4 a0 = *(const float4*)ap;
            float4 a1 = *(const float4*)(ap + 4);
            union { __hip_bfloat162 h2[4]; bf16x8 v; } ua;
            ua.h2[0] = __float22bfloat162_rn(make_float2(a0.x, a0.y));
            ua.h2[1] = __float22bfloat162_rn(make_float2(a0.z, a0.w));
            ua.h2[2] = __float22bfloat162_rn(make_float2(a1.x, a1.y));
            ua.h2[3] = __float22bfloat162_rn(make_float2(a1.z, a1.w));
            *(bf16x8*)(As + ar * KP + ak) = ua.v;
        }
        // ---- stage Wt tile (256 n x 32 k) bf16 copy; thread t = row n ----
        {
            const __hip_bfloat16* wp = Wt + (size_t)(kt >> 5) * 8192 + t * 32;
            bf16x8 w0 = *(const bf16x8*)(wp + 0);
            bf16x8 w1 = *(const bf16x8*)(wp + 8);
            bf16x8 w2 = *(const bf16x8*)(wp + 16);
            bf16x8 w3 = *(const bf16x8*)(wp + 24);
            __hip_bfloat16* wd = Ws + t * KP;
            *(bf16x8*)(wd + 0)  = w0;
            *(bf16x8*)(wd + 8)  = w1;
            *(bf16x8*)(wd + 16) = w2;
            *(bf16x8*)(wd + 24) = w3;
        }
        __syncthreads();

        // ---- MFMA: 2 k-steps of 16, 2x2 tiles of 32x32 ----
#pragma unroll
        for (int kk = 0; kk < 32; kk += 16) {
            bf16x8 af0 = *(const bf16x8*)(As + (0 * 32 + lm) * KP + kk + lk);
            bf16x8 af1 = *(const bf16x8*)(As + (1 * 32 + lm) * KP + kk + lk);
            bf16x8 bf0 = *(const bf16x8*)(Ws + (wave * 64 + 0 * 32 + lm) * KP + kk + lk);
            bf16x8 bf1 = *(const bf16x8*)(Ws + (wave * 64 + 1 * 32 + lm) * KP + kk + lk);
            acc[0][0] = __builtin_amdgcn_mfma_f32_32x32x16_bf16(af0, bf0, acc[0][0], 0, 0, 0);
            acc[0][1] = __builtin_amdgcn_mfma_f32_32x32x16_bf16(af0, bf1, acc[0][1], 0, 0, 0);
            acc[1][0] = __builtin_amdgcn_mfma_f32_32x32x16_bf16(af1, bf0, acc[1][0], 0, 0, 0);
            acc[1][1] = __builtin_amdgcn_mfma_f32_32x32x16_bf16(af1, bf1, acc[1][1], 0, 0, 0);
        }
        __syncthreads();
    }

    // ---- epilogue: bias + bf16 + permuted store (b, h, pos, d) ----
#pragma unroll
    for (int ni = 0; ni < 2; ni++) {
        const int n  = wave * 64 + ni * 32 + lm;
        const float bn = bias[n];
        const int h  = n >> 5;
        const int d  = n & 31;
#pragma unroll
        for (int mi = 0; mi < 2; mi++) {
#pragma unroll
            for (int r = 0; r < 16; r++) {
                int rl = (r & 3) + 8 * (r >> 2) + 4 * (lane >> 5);
                int m  = m0 + mi * 32 + rl;
                int b  = m / NT;
                int pos = m - b * NT;
                V[((size_t)(b * NH + h) * NT + pos) * HD + d] =
                    __float2bfloat16(acc[mi][ni][r] + bn);
            }
        }
    }
}

// ---------------------------------------------------------------------------
// Kernel 2: off_raw = query @ W_off + b_off ; attn_raw = query @ W_attn + b_attn
// ---------------------------------------------------------------------------
__global__ __launch_bounds__(256) void k_offattn(
    const float* __restrict__ Q,       // (4800, 256)
    const float* __restrict__ Woff,    // (256, 192)
    const float* __restrict__ boff,    // (192,)
    const float* __restrict__ Wattn,   // (256, 96)
    const float* __restrict__ battn,   // (96,)
    float* __restrict__ off_out,       // (4800, 192)
    float* __restrict__ attn_out)      // (4800, 96)
{
    __shared__ float Qs[32 * 256];
    const int t  = threadIdx.x;
    const int m0 = blockIdx.x * 32;
#pragma unroll
    for (int i = 0; i < 8; i++) {
        int f  = t + i * 256;
        int r  = f >> 6;
        int cq = (f & 63) * 4;
        *(float4*)(&Qs[r * 256 + cq]) =
            *(const float4*)(Q + (size_t)(m0 + r) * 256 + cq);
    }
    __syncthreads();

    for (int pass = 0; pass < 2; pass++) {
        int c = t + (pass << 8);
        if (c >= 288) break;
        float acc[32];
#pragma unroll
        for (int r = 0; r < 32; r++) acc[r] = 0.f;
        const bool isoff = (c < 192);
        const float* Wp  = isoff ? (Woff + c) : (Wattn + (c - 192));
        const int stride = isoff ? 192 : 96;
        for (int k = 0; k < 256; k += 4) {
            float w0 = Wp[(k + 0) * stride];
            float w1 = Wp[(k + 1) * stride];
            float w2 = Wp[(k + 2) * stride];
            float w3 = Wp[(k + 3) * stride];
#pragma unroll
            for (int r = 0; r < 32; r++) {
                float4 qv = *(float4*)(&Qs[r * 256 + k]);
                acc[r] = fmaf(qv.x, w0,
                         fmaf(qv.y, w1,
                         fmaf(qv.z, w2,
                         fmaf(qv.w, w3, acc[r]))));
            }
        }
        float bias_ = isoff ? boff[c] : battn[c - 192];
        if (isoff) {
#pragma unroll
            for (int r = 0; r < 32; r++)
                off_out[(size_t)(m0 + r) * 192 + c] = acc[r] + bias_;
        } else {
            int ca = c - 192;
#pragma unroll
            for (int r = 0; r < 32; r++)
                attn_out[(size_t)(m0 + r) * 96 + ca] = acc[r] + bias_;
        }
    }
}

// ---------------------------------------------------------------------------
// Kernel 3: softmax(attn) + sampling locations + bilinear gather + weighted sum
// ---------------------------------------------------------------------------
__global__ __launch_bounds__(256) void k_sample(
    const float* __restrict__ off_raw,   // (4800, 192)  (h,l,p,2)
    const float* __restrict__ attn_raw,  // (4800, 96)   (h, l*4+p)
    const float* __restrict__ refp,      // (16, 300, 3, 2)
    const __hip_bfloat16* __restrict__ V,// (16, 8, 8400, 32)
    float* __restrict__ sampled)         // (4800, 256)
{
    const int t  = threadIdx.x;
    const int bq = blockIdx.x;
    const int b  = bq / LQ;

    __shared__ float aw[96];
    __shared__ float sx[96];
    __shared__ float sy[96];

    const float dims[3] = {80.f, 40.f, 20.f};

    if (t < 96) {
        int h = t / 12, lp = t - h * 12, l = lp >> 2, p = lp & 3;
        float ox = off_raw[(size_t)bq * 192 + ((h * 3 + l) * 4 + p) * 2 + 0];
        float oy = off_raw[(size_t)bq * 192 + ((h * 3 + l) * 4 + p) * 2 + 1];
        float rx = refp[(size_t)bq * 6 + l * 2 + 0];
        float ry = refp[(size_t)bq * 6 + l * 2 + 1];
        float D  = dims[l];
        float lx = rx + ox / D;
        float ly = ry + oy / D;
        sx[t] = lx * D - 0.5f;
        sy[t] = ly * D - 0.5f;
    }
    if (t < 8) {
        float v[12];
        float mx = -1e30f;
#pragma unroll
        for (int i = 0; i < 12; i++) {
            v[i] = attn_raw[(size_t)bq * 96 + t * 12 + i];
            mx = fmaxf(mx, v[i]);
        }
        float s = 0.f;
#pragma unroll
        for (int i = 0; i < 12; i++) { v[i] = expf(v[i] - mx); s += v[i]; }
        float inv = 1.f / s;
#pragma unroll
        for (int i = 0; i < 12; i++) aw[t * 12 + i] = v[i] * inv;
    }
    __syncthreads();

    const int h = t >> 5, d = t & 31;
    const __hip_bfloat16* vb = V + (size_t)(b * NH + h) * NT * HD + d;

    const int starts[3] = {0, 6400, 8000};
    const int idim[3]   = {80, 40, 20};

    float acc = 0.f;
#pragma unroll
    for (int l = 0; l < 3; l++) {
        const int Dl = idim[l];
        const int st = starts[l];
#pragma unroll
        for (int p = 0; p < 4; p++) {
            const int s = h * 12 + l * 4 + p;
            float ix = sx[s], iy = sy[s];
            float w  = aw[s];
            float fix = floorf(ix), fiy = floorf(iy);
            int ix0 = (int)fix, iy0 = (int)fiy;
            int ix1 = ix0 + 1, iy1 = iy0 + 1;
            float fx = ix - fix, fy = iy - fiy;

            float mx0 = (ix0 >= 0 && ix0 < Dl) ? 1.f : 0.f;
            float mx1 = (ix1 >= 0 && ix1 < Dl) ? 1.f : 0.f;
            float my0 = (iy0 >= 0 && iy0 < Dl) ? 1.f : 0.f;
            float my1 = (iy1 >= 0 && iy1 < Dl) ? 1.f : 0.f;

            int cx0 = min(max(ix0, 0), Dl - 1);
            int cx1 = min(max(ix1, 0), Dl - 1);
            int cy0 = min(max(iy0, 0), Dl - 1);
            int cy1 = min(max(iy1, 0), Dl - 1);

            float v00 = mx0 * my0 * __bfloat162float(vb[(size_t)(st + cy0 * Dl + cx0) * HD]);
            float v01 = mx1 * my0 * __bfloat162float(vb[(size_t)(st + cy0 * Dl + cx1) * HD]);
            float v10 = mx0 * my1 * __bfloat162float(vb[(size_t)(st + cy1 * Dl + cx0) * HD]);
            float v11 = mx1 * my1 * __bfloat162float(vb[(size_t)(st + cy1 * Dl + cx1) * HD]);

            float sval = (1.f - fx) * (1.f - fy) * v00 + fx * (1.f - fy) * v01
                       + (1.f - fx) * fy * v10 + fx * fy * v11;
            acc = fmaf(w, sval, acc);
        }
    }
    sampled[(size_t)bq * 256 + t] = acc;
}

// ---------------------------------------------------------------------------
// Kernel 4: out = sampled @ W_out + b_out.  BM=32, BN=256, 4x8 blocking.
// ---------------------------------------------------------------------------
__global__ __launch_bounds__(256) void k_outproj(
    const float* __restrict__ A,      // (4800, 256)
    const float* __restrict__ W,      // (256, 256)
    const float* __restrict__ bias,   // (256,)
    float* __restrict__ out)          // (4800, 256)
{
    __shared__ float As[32 * 33];
    __shared__ float Ws[32 * 256];
    const int t   = threadIdx.x;
    const int m0  = blockIdx.x * 32;
    const int tn  = (t & 31) * 8;
    const int tmg = (t >> 5) * 4;

    float acc[4][8];
#pragma unroll
    for (int i = 0; i < 4; i++)
#pragma unroll
        for (int j = 0; j < 8; j++) acc[i][j] = 0.f;

    for (int kt = 0; kt < 256; kt += 32) {
        {
            int f  = t;
            int r  = f >> 3;
            int kq = (f & 7) * 4;
            float4 a4 = *(const float4*)(A + (size_t)(m0 + r) * 256 + kt + kq);
            float* dst = &As[r * 33 + kq];
            dst[0] = a4.x; dst[1] = a4.y; dst[2] = a4.z; dst[3] = a4.w;
        }
#pragma unroll
        for (int i = 0; i < 8; i++) {
            int f  = t + i * 256;
            int kr = f >> 6;
            int cq = (f & 63) * 4;
            *(float4*)(&Ws[kr * 256 + cq]) =
                *(const float4*)(W + (size_t)(kt + kr) * 256 + cq);
        }
        __syncthreads();
#pragma unroll 4
        for (int k = 0; k < 32; k++) {
            float a[4], w[8];
#pragma unroll
            for (int i = 0; i < 4; i++) a[i] = As[(tmg + i) * 33 + k];
            float4 w0 = *(float4*)(&Ws[k * 256 + tn]);
            float4 w1 = *(float4*)(&Ws[k * 256 + tn + 4]);
            w[0] = w0.x; w[1] = w0.y; w[2] = w0.z; w[3] = w0.w;
            w[4] = w1.x; w[5] = w1.y; w[6] = w1.z; w[7] = w1.w;
#pragma unroll
            for (int i = 0; i < 4; i++)
#pragma unroll
                for (int j = 0; j < 8; j++)
                    acc[i][j] = fmaf(a[i], w[j], acc[i][j]);
        }
        __syncthreads();
    }

    float bv[8];
#pragma unroll
    for (int j = 0; j < 8; j++) bv[j] = bias[tn + j];
#pragma unroll
    for (int i = 0; i < 4; i++) {
        int m = m0 + tmg + i;
        float4 o0, o1;
        o0.x = acc[i][0] + bv[0]; o0.y = acc[i][1] + bv[1];
        o0.z = acc[i][2] + bv[2]; o0.w = acc[i][3] + bv[3];
        o1.x = acc[i][4] + bv[4]; o1.y = acc[i][5] + bv[5];
        o1.z = acc[i][6] + bv[6]; o1.w = acc[i][7] + bv[7];
        *(float4*)(out + (size_t)m * 256 + tn)     = o0;
        *(float4*)(out + (size_t)m * 256 + tn + 4) = o1;
    }
}

// ---------------------------------------------------------------------------
extern "C" void kernel_launch(void* const* d_in, const int* in_sizes, int n_in,
                              void* d_out, int out_size, void* d_ws, size_t ws_size,
                              hipStream_t stream) {
    const float* query  = (const float*)d_in[0];
    const float* refp   = (const float*)d_in[1];
    const float* inputf = (const float*)d_in[2];
    const float* W_off  = (const float*)d_in[3];
    const float* b_off  = (const float*)d_in[4];
    const float* W_attn = (const float*)d_in[5];
    const float* b_attn = (const float*)d_in[6];
    const float* W_val  = (const float*)d_in[7];
    const float* b_val  = (const float*)d_in[8];
    const float* W_out  = (const float*)d_in[9];
    const float* b_out  = (const float*)d_in[10];
    float* out = (float*)d_out;

    char* ws = (char*)d_ws;
    const size_t value_bytes = (size_t)BB * NH * NT * HD * 2;   // 68,812,800
    const size_t off_bytes   = (size_t)QROWS * 192 * 4;         //  3,686,400
    const size_t attn_bytes  = (size_t)QROWS * 96 * 4;          //  1,843,200
    __hip_bfloat16* value = (__hip_bfloat16*)ws;
    float* off_raw  = (float*)(ws + value_bytes);
    float* attn_raw = (float*)(ws + value_bytes + off_bytes);
    float* sampled  = (float*)(ws + value_bytes + off_bytes + attn_bytes);
    // Wt aliases `sampled`: Wt is only used by k_wt/k_valproj, which complete
    // before k_sample writes `sampled`. Keeps ws usage at the proven 79.26 MB.
    __hip_bfloat16* Wt = (__hip_bfloat16*)sampled;

    k_wt<<<256, 256, 0, stream>>>(W_val, Wt);
    k_valproj<<<MROWS / 64, 256, 0, stream>>>(inputf, Wt, b_val, value);
    k_offattn<<<QROWS / 32, 256, 0, stream>>>(query, W_off, b_off, W_attn, b_attn,
                                              off_raw, attn_raw);
    k_sample<<<QROWS, 256, 0, stream>>>(off_raw, attn_raw, refp, value, sampled);
    k_outproj<<<QROWS / 32, 256, 0, stream>>>(sampled, W_out, b_out, out);
}

// Round 3
// 326.625 us; speedup vs baseline: 1.8205x; 1.3935x over previous
//
#include <hip/hip_runtime.h>
#include <hip/hip_bf16.h>

#define DM 256
#define NH 8
#define HD 32
#define NLV 3
#define NPT 4
#define NLP 12
#define BB 16
#define LQ 300
#define NT 8400
#define MROWS (BB * NT)      // 134400
#define QROWS (BB * LQ)      // 4800
#define KP 40                // padded LDS K-stride (bf16 elems), 80 B, 16-B aligned

typedef __bf16 bf16x8 __attribute__((ext_vector_type(8)));
typedef float  f32x16 __attribute__((ext_vector_type(16)));

// ---------------------------------------------------------------------------
// Kernel 0: pre-transpose + pre-tile weights to bf16.
// blocks 0..255   -> Wt  [ktile(8)][n(256)][k(32)]  from W_val
// blocks 256..543 -> Wt2 [ktile(8)][n(288)][k(32)]  from [W_off | W_attn]
// ---------------------------------------------------------------------------
__global__ void k_wt(const float* __restrict__ W_val,
                     const float* __restrict__ W_off,
                     const float* __restrict__ W_attn,
                     __hip_bfloat16* __restrict__ Wt,
                     __hip_bfloat16* __restrict__ Wt2)
{
    const int n = blockIdx.x;
    const int k = threadIdx.x;
    if (n < 256) {
        Wt[(size_t)(k >> 5) * 8192 + n * 32 + (k & 31)] =
            __float2bfloat16(W_val[(size_t)k * 256 + n]);
    } else {
        const int n2 = n - 256;   // 0..287
        float v = (n2 < 192) ? W_off[(size_t)k * 192 + n2]
                             : W_attn[(size_t)k * 96 + (n2 - 192)];
        Wt2[(size_t)(k >> 5) * 9216 + n2 * 32 + (k & 31)] = __float2bfloat16(v);
    }
}

// ---------------------------------------------------------------------------
// Kernel 1: value = input_flatten @ W_val + b_val (bf16 MFMA), permuted store
// to (b, h, pos, d) bf16.  Block: 64 rows x 256 cols, 256 thr = 4 waves.
// ---------------------------------------------------------------------------
__global__ __launch_bounds__(256) void k_valproj(
    const float* __restrict__ A,             // (134400, 256) fp32
    const __hip_bfloat16* __restrict__ Wt,   // tiled bf16 W^T
    const float* __restrict__ bias,          // (256,)
    __hip_bfloat16* __restrict__ V)          // (16, 8, 8400, 32)
{
    __shared__ __hip_bfloat16 As[64 * KP];
    __shared__ __hip_bfloat16 Ws[256 * KP];

    const int t    = threadIdx.x;
    const int m0   = blockIdx.x * 64;
    const int wave = t >> 6;
    const int lane = t & 63;
    const int lm   = lane & 31;
    const int lk   = (lane >> 5) * 8;

    f32x16 acc[2][2];
#pragma unroll
    for (int i = 0; i < 2; i++)
#pragma unroll
        for (int j = 0; j < 2; j++)
#pragma unroll
            for (int e = 0; e < 16; e++) acc[i][j][e] = 0.f;

    const int ar = t >> 2;
    const int ak = (t & 3) * 8;

    for (int kt = 0; kt < 256; kt += 32) {
        {
            const float* ap = A + (size_t)(m0 + ar) * 256 + kt + ak;
            float4 a0 = *(const float4*)ap;
            float4 a1 = *(const float4*)(ap + 4);
            union { __hip_bfloat162 h2[4]; bf16x8 v; } ua;
            ua.h2[0] = __float22bfloat162_rn(make_float2(a0.x, a0.y));
            ua.h2[1] = __float22bfloat162_rn(make_float2(a0.z, a0.w));
            ua.h2[2] = __float22bfloat162_rn(make_float2(a1.x, a1.y));
            ua.h2[3] = __float22bfloat162_rn(make_float2(a1.z, a1.w));
            *(bf16x8*)(As + ar * KP + ak) = ua.v;
        }
        {
            const __hip_bfloat16* wp = Wt + (size_t)(kt >> 5) * 8192 + t * 32;
            bf16x8 w0 = *(const bf16x8*)(wp + 0);
            bf16x8 w1 = *(const bf16x8*)(wp + 8);
            bf16x8 w2 = *(const bf16x8*)(wp + 16);
            bf16x8 w3 = *(const bf16x8*)(wp + 24);
            __hip_bfloat16* wd = Ws + t * KP;
            *(bf16x8*)(wd + 0)  = w0;
            *(bf16x8*)(wd + 8)  = w1;
            *(bf16x8*)(wd + 16) = w2;
            *(bf16x8*)(wd + 24) = w3;
        }
        __syncthreads();

#pragma unroll
        for (int kk = 0; kk < 32; kk += 16) {
            bf16x8 af0 = *(const bf16x8*)(As + (0 * 32 + lm) * KP + kk + lk);
            bf16x8 af1 = *(const bf16x8*)(As + (1 * 32 + lm) * KP + kk + lk);
            bf16x8 bf0 = *(const bf16x8*)(Ws + (wave * 64 + 0 * 32 + lm) * KP + kk + lk);
            bf16x8 bf1 = *(const bf16x8*)(Ws + (wave * 64 + 1 * 32 + lm) * KP + kk + lk);
            acc[0][0] = __builtin_amdgcn_mfma_f32_32x32x16_bf16(af0, bf0, acc[0][0], 0, 0, 0);
            acc[0][1] = __builtin_amdgcn_mfma_f32_32x32x16_bf16(af0, bf1, acc[0][1], 0, 0, 0);
            acc[1][0] = __builtin_amdgcn_mfma_f32_32x32x16_bf16(af1, bf0, acc[1][0], 0, 0, 0);
            acc[1][1] = __builtin_amdgcn_mfma_f32_32x32x16_bf16(af1, bf1, acc[1][1], 0, 0, 0);
        }
        __syncthreads();
    }

#pragma unroll
    for (int ni = 0; ni < 2; ni++) {
        const int n  = wave * 64 + ni * 32 + lm;
        const float bn = bias[n];
        const int h  = n >> 5;
        const int d  = n & 31;
#pragma unroll
        for (int mi = 0; mi < 2; mi++) {
#pragma unroll
            for (int r = 0; r < 16; r++) {
                int rl = (r & 3) + 8 * (r >> 2) + 4 * (lane >> 5);
                int m  = m0 + mi * 32 + rl;
                int b  = m / NT;
                int pos = m - b * NT;
                V[((size_t)(b * NH + h) * NT + pos) * HD + d] =
                    __float2bfloat16(acc[mi][ni][r] + bn);
            }
        }
    }
}

// ---------------------------------------------------------------------------
// Kernel 2 (MFMA): [off_raw | attn_raw] = query @ [W_off | W_attn] + bias.
// Block: 32 rows x 288 cols, 192 threads = 3 waves; wave w covers n in
// [w*96, w*96+96) = 3 tiles of 32x32.  BK=32.
// ---------------------------------------------------------------------------
__global__ __launch_bounds__(192) void k_offattn(
    const float* __restrict__ Q,             // (4800, 256)
    const __hip_bfloat16* __restrict__ Wt2,  // tiled bf16 [W_off|W_attn]^T
    const float* __restrict__ boff,          // (192,)
    const float* __restrict__ battn,         // (96,)
    float* __restrict__ off_out,             // (4800, 192)
    float* __restrict__ attn_out)            // (4800, 96)
{
    __shared__ __hip_bfloat16 As[32 * KP];
    __shared__ __hip_bfloat16 Ws[288 * KP];

    const int t    = threadIdx.x;
    const int m0   = blockIdx.x * 32;
    const int wave = t >> 6;       // 0..2
    const int lane = t & 63;
    const int lm   = lane & 31;
    const int lk   = (lane >> 5) * 8;

    f32x16 acc[3];
#pragma unroll
    for (int j = 0; j < 3; j++)
#pragma unroll
        for (int e = 0; e < 16; e++) acc[j][e] = 0.f;

    for (int kt = 0; kt < 256; kt += 32) {
        // stage A (32 rows x 32 k) fp32 -> bf16; threads 0..127
        if (t < 128) {
            const int ar = t >> 2;
            const int ak = (t & 3) * 8;
            const float* ap = Q + (size_t)(m0 + ar) * 256 + kt + ak;
            float4 a0 = *(const float4*)ap;
            float4 a1 = *(const float4*)(ap + 4);
            union { __hip_bfloat162 h2[4]; bf16x8 v; } ua;
            ua.h2[0] = __float22bfloat162_rn(make_float2(a0.x, a0.y));
            ua.h2[1] = __float22bfloat162_rn(make_float2(a0.z, a0.w));
            ua.h2[2] = __float22bfloat162_rn(make_float2(a1.x, a1.y));
            ua.h2[3] = __float22bfloat162_rn(make_float2(a1.z, a1.w));
            *(bf16x8*)(As + ar * KP + ak) = ua.v;
        }
        // stage W (288 n x 32 k): thread t handles row t, and row t+192 if t<96
        {
            const __hip_bfloat16* wp = Wt2 + (size_t)(kt >> 5) * 9216 + t * 32;
            __hip_bfloat16* wd = Ws + t * KP;
            *(bf16x8*)(wd + 0)  = *(const bf16x8*)(wp + 0);
            *(bf16x8*)(wd + 8)  = *(const bf16x8*)(wp + 8);
            *(bf16x8*)(wd + 16) = *(const bf16x8*)(wp + 16);
            *(bf16x8*)(wd + 24) = *(const bf16x8*)(wp + 24);
            if (t < 96) {
                const __hip_bfloat16* wp2 = Wt2 + (size_t)(kt >> 5) * 9216 + (t + 192) * 32;
                __hip_bfloat16* wd2 = Ws + (t + 192) * KP;
                *(bf16x8*)(wd2 + 0)  = *(const bf16x8*)(wp2 + 0);
                *(bf16x8*)(wd2 + 8)  = *(const bf16x8*)(wp2 + 8);
                *(bf16x8*)(wd2 + 16) = *(const bf16x8*)(wp2 + 16);
                *(bf16x8*)(wd2 + 24) = *(const bf16x8*)(wp2 + 24);
            }
        }
        __syncthreads();

#pragma unroll
        for (int kk = 0; kk < 32; kk += 16) {
            bf16x8 af = *(const bf16x8*)(As + lm * KP + kk + lk);
#pragma unroll
            for (int j = 0; j < 3; j++) {
                bf16x8 bf = *(const bf16x8*)(Ws + (wave * 96 + j * 32 + lm) * KP + kk + lk);
                acc[j] = __builtin_amdgcn_mfma_f32_32x32x16_bf16(af, bf, acc[j], 0, 0, 0);
            }
        }
        __syncthreads();
    }

    // epilogue: branch is wave-uniform per j (n-tile never straddles 192)
#pragma unroll
    for (int j = 0; j < 3; j++) {
        const int n = wave * 96 + j * 32 + lm;
        const float bias_ = (n < 192) ? boff[n] : battn[n - 192];
#pragma unroll
        for (int r = 0; r < 16; r++) {
            int rl = (r & 3) + 8 * (r >> 2) + 4 * (lane >> 5);
            int m  = m0 + rl;
            float v = acc[j][r] + bias_;
            if (n < 192) off_out[(size_t)m * 192 + n] = v;
            else         attn_out[(size_t)m * 96 + (n - 192)] = v;
        }
    }
}

// ---------------------------------------------------------------------------
// Kernel 3: softmax(attn) + sampling locations + bilinear gather + weighted sum
// ---------------------------------------------------------------------------
__global__ __launch_bounds__(256) void k_sample(
    const float* __restrict__ off_raw,   // (4800, 192)  (h,l,p,2)
    const float* __restrict__ attn_raw,  // (4800, 96)   (h, l*4+p)
    const float* __restrict__ refp,      // (16, 300, 3, 2)
    const __hip_bfloat16* __restrict__ V,// (16, 8, 8400, 32)
    float* __restrict__ sampled)         // (4800, 256)
{
    const int t  = threadIdx.x;
    const int bq = blockIdx.x;
    const int b  = bq / LQ;

    __shared__ float aw[96];
    __shared__ float sx[96];
    __shared__ float sy[96];

    const float dims[3] = {80.f, 40.f, 20.f};

    if (t < 96) {
        int h = t / 12, lp = t - h * 12, l = lp >> 2, p = lp & 3;
        float ox = off_raw[(size_t)bq * 192 + ((h * 3 + l) * 4 + p) * 2 + 0];
        float oy = off_raw[(size_t)bq * 192 + ((h * 3 + l) * 4 + p) * 2 + 1];
        float rx = refp[(size_t)bq * 6 + l * 2 + 0];
        float ry = refp[(size_t)bq * 6 + l * 2 + 1];
        float D  = dims[l];
        float lx = rx + ox / D;
        float ly = ry + oy / D;
        sx[t] = lx * D - 0.5f;
        sy[t] = ly * D - 0.5f;
    }
    if (t < 8) {
        float v[12];
        float mx = -1e30f;
#pragma unroll
        for (int i = 0; i < 12; i++) {
            v[i] = attn_raw[(size_t)bq * 96 + t * 12 + i];
            mx = fmaxf(mx, v[i]);
        }
        float s = 0.f;
#pragma unroll
        for (int i = 0; i < 12; i++) { v[i] = expf(v[i] - mx); s += v[i]; }
        float inv = 1.f / s;
#pragma unroll
        for (int i = 0; i < 12; i++) aw[t * 12 + i] = v[i] * inv;
    }
    __syncthreads();

    const int h = t >> 5, d = t & 31;
    const __hip_bfloat16* vb = V + (size_t)(b * NH + h) * NT * HD + d;

    const int starts[3] = {0, 6400, 8000};
    const int idim[3]   = {80, 40, 20};

    float acc = 0.f;
#pragma unroll
    for (int l = 0; l < 3; l++) {
        const int Dl = idim[l];
        const int st = starts[l];
#pragma unroll
        for (int p = 0; p < 4; p++) {
            const int s = h * 12 + l * 4 + p;
            float ix = sx[s], iy = sy[s];
            float w  = aw[s];
            float fix = floorf(ix), fiy = floorf(iy);
            int ix0 = (int)fix, iy0 = (int)fiy;
            int ix1 = ix0 + 1, iy1 = iy0 + 1;
            float fx = ix - fix, fy = iy - fiy;

            float mx0 = (ix0 >= 0 && ix0 < Dl) ? 1.f : 0.f;
            float mx1 = (ix1 >= 0 && ix1 < Dl) ? 1.f : 0.f;
            float my0 = (iy0 >= 0 && iy0 < Dl) ? 1.f : 0.f;
            float my1 = (iy1 >= 0 && iy1 < Dl) ? 1.f : 0.f;

            int cx0 = min(max(ix0, 0), Dl - 1);
            int cx1 = min(max(ix1, 0), Dl - 1);
            int cy0 = min(max(iy0, 0), Dl - 1);
            int cy1 = min(max(iy1, 0), Dl - 1);

            float v00 = mx0 * my0 * __bfloat162float(vb[(size_t)(st + cy0 * Dl + cx0) * HD]);
            float v01 = mx1 * my0 * __bfloat162float(vb[(size_t)(st + cy0 * Dl + cx1) * HD]);
            float v10 = mx0 * my1 * __bfloat162float(vb[(size_t)(st + cy1 * Dl + cx0) * HD]);
            float v11 = mx1 * my1 * __bfloat162float(vb[(size_t)(st + cy1 * Dl + cx1) * HD]);

            float sval = (1.f - fx) * (1.f - fy) * v00 + fx * (1.f - fy) * v01
                       + (1.f - fx) * fy * v10 + fx * fy * v11;
            acc = fmaf(w, sval, acc);
        }
    }
    sampled[(size_t)bq * 256 + t] = acc;
}

// ---------------------------------------------------------------------------
// Kernel 4: out = sampled @ W_out + b_out.  BM=32, BN=256, 4x8 blocking.
// ---------------------------------------------------------------------------
__global__ __launch_bounds__(256) void k_outproj(
    const float* __restrict__ A,      // (4800, 256)
    const float* __restrict__ W,      // (256, 256)
    const float* __restrict__ bias,   // (256,)
    float* __restrict__ out)          // (4800, 256)
{
    __shared__ float As[32 * 33];
    __shared__ float Ws[32 * 256];
    const int t   = threadIdx.x;
    const int m0  = blockIdx.x * 32;
    const int tn  = (t & 31) * 8;
    const int tmg = (t >> 5) * 4;

    float acc[4][8];
#pragma unroll
    for (int i = 0; i < 4; i++)
#pragma unroll
        for (int j = 0; j < 8; j++) acc[i][j] = 0.f;

    for (int kt = 0; kt < 256; kt += 32) {
        {
            int f  = t;
            int r  = f >> 3;
            int kq = (f & 7) * 4;
            float4 a4 = *(const float4*)(A + (size_t)(m0 + r) * 256 + kt + kq);
            float* dst = &As[r * 33 + kq];
            dst[0] = a4.x; dst[1] = a4.y; dst[2] = a4.z; dst[3] = a4.w;
        }
#pragma unroll
        for (int i = 0; i < 8; i++) {
            int f  = t + i * 256;
            int kr = f >> 6;
            int cq = (f & 63) * 4;
            *(float4*)(&Ws[kr * 256 + cq]) =
                *(const float4*)(W + (size_t)(kt + kr) * 256 + cq);
        }
        __syncthreads();
#pragma unroll 4
        for (int k = 0; k < 32; k++) {
            float a[4], w[8];
#pragma unroll
            for (int i = 0; i < 4; i++) a[i] = As[(tmg + i) * 33 + k];
            float4 w0 = *(float4*)(&Ws[k * 256 + tn]);
            float4 w1 = *(float4*)(&Ws[k * 256 + tn + 4]);
            w[0] = w0.x; w[1] = w0.y; w[2] = w0.z; w[3] = w0.w;
            w[4] = w1.x; w[5] = w1.y; w[6] = w1.z; w[7] = w1.w;
#pragma unroll
            for (int i = 0; i < 4; i++)
#pragma unroll
                for (int j = 0; j < 8; j++)
                    acc[i][j] = fmaf(a[i], w[j], acc[i][j]);
        }
        __syncthreads();
    }

    float bv[8];
#pragma unroll
    for (int j = 0; j < 8; j++) bv[j] = bias[tn + j];
#pragma unroll
    for (int i = 0; i < 4; i++) {
        int m = m0 + tmg + i;
        float4 o0, o1;
        o0.x = acc[i][0] + bv[0]; o0.y = acc[i][1] + bv[1];
        o0.z = acc[i][2] + bv[2]; o0.w = acc[i][3] + bv[3];
        o1.x = acc[i][4] + bv[4]; o1.y = acc[i][5] + bv[5];
        o1.z = acc[i][6] + bv[6]; o1.w = acc[i][7] + bv[7];
        *(float4*)(out + (size_t)m * 256 + tn)     = o0;
        *(float4*)(out + (size_t)m * 256 + tn + 4) = o1;
    }
}

// ---------------------------------------------------------------------------
extern "C" void kernel_launch(void* const* d_in, const int* in_sizes, int n_in,
                              void* d_out, int out_size, void* d_ws, size_t ws_size,
                              hipStream_t stream) {
    const float* query  = (const float*)d_in[0];
    const float* refp   = (const float*)d_in[1];
    const float* inputf = (const float*)d_in[2];
    const float* W_off  = (const float*)d_in[3];
    const float* b_off  = (const float*)d_in[4];
    const float* W_attn = (const float*)d_in[5];
    const float* b_attn = (const float*)d_in[6];
    const float* W_val  = (const float*)d_in[7];
    const float* b_val  = (const float*)d_in[8];
    const float* W_out  = (const float*)d_in[9];
    const float* b_out  = (const float*)d_in[10];
    float* out = (float*)d_out;

    char* ws = (char*)d_ws;
    const size_t value_bytes = (size_t)BB * NH * NT * HD * 2;   // 68,812,800
    const size_t off_bytes   = (size_t)QROWS * 192 * 4;         //  3,686,400
    const size_t attn_bytes  = (size_t)QROWS * 96 * 4;          //  1,843,200
    __hip_bfloat16* value = (__hip_bfloat16*)ws;
    float* off_raw  = (float*)(ws + value_bytes);
    float* attn_raw = (float*)(ws + value_bytes + off_bytes);
    float* sampled  = (float*)(ws + value_bytes + off_bytes + attn_bytes);
    // Wt/Wt2 alias `sampled` (4.9 MB): consumed by k_valproj/k_offattn, which
    // complete before k_sample writes `sampled`.
    __hip_bfloat16* Wt  = (__hip_bfloat16*)sampled;                 // 131,072 B
    __hip_bfloat16* Wt2 = (__hip_bfloat16*)((char*)sampled + 131072); // 147,456 B

    k_wt<<<544, 256, 0, stream>>>(W_val, W_off, W_attn, Wt, Wt2);
    k_valproj<<<MROWS / 64, 256, 0, stream>>>(inputf, Wt, b_val, value);
    k_offattn<<<QROWS / 32, 192, 0, stream>>>(query, Wt2, b_off, b_attn,
                                              off_raw, attn_raw);
    k_sample<<<QROWS, 256, 0, stream>>>(off_raw, attn_raw, refp, value, sampled);
    k_outproj<<<QROWS / 32, 256, 0, stream>>>(sampled, W_out, b_out, out);
}

// Round 4
// 283.398 us; speedup vs baseline: 2.0982x; 1.1525x over previous
//
#include <hip/hip_runtime.h>
#include <hip/hip_bf16.h>

#define DM 256
#define NH 8
#define HD 32
#define NLV 3
#define NPT 4
#define NLP 12
#define BB 16
#define LQ 300
#define NT 8400
#define MROWS (BB * NT)      // 134400
#define QROWS (BB * LQ)      // 4800
#define KP 40                // padded LDS K-stride (bf16 elems), 80 B, 16-B aligned

typedef __bf16 bf16x8 __attribute__((ext_vector_type(8)));
typedef __bf16 bf16x4 __attribute__((ext_vector_type(4)));
typedef float  f32x16 __attribute__((ext_vector_type(16)));

// ---------------------------------------------------------------------------
// Kernel 0: pre-transpose + pre-tile weights to bf16.
// blocks 0..255   -> Wt  [ktile(8)][n(256)][k(32)]  from W_val
// blocks 256..543 -> Wt2 [ktile(8)][n(288)][k(32)]  from [W_off | W_attn]
// blocks 544..799 -> Wt3 [ktile(8)][n(256)][k(32)]  from W_out
// ---------------------------------------------------------------------------
__global__ void k_wt(const float* __restrict__ W_val,
                     const float* __restrict__ W_off,
                     const float* __restrict__ W_attn,
                     const float* __restrict__ W_out,
                     __hip_bfloat16* __restrict__ Wt,
                     __hip_bfloat16* __restrict__ Wt2,
                     __hip_bfloat16* __restrict__ Wt3)
{
    const int n = blockIdx.x;
    const int k = threadIdx.x;
    if (n < 256) {
        Wt[(size_t)(k >> 5) * 8192 + n * 32 + (k & 31)] =
            __float2bfloat16(W_val[(size_t)k * 256 + n]);
    } else if (n < 544) {
        const int n2 = n - 256;   // 0..287
        float v = (n2 < 192) ? W_off[(size_t)k * 192 + n2]
                             : W_attn[(size_t)k * 96 + (n2 - 192)];
        Wt2[(size_t)(k >> 5) * 9216 + n2 * 32 + (k & 31)] = __float2bfloat16(v);
    } else {
        const int n3 = n - 544;   // 0..255
        Wt3[(size_t)(k >> 5) * 8192 + n3 * 32 + (k & 31)] =
            __float2bfloat16(W_out[(size_t)k * 256 + n3]);
    }
}

// ---------------------------------------------------------------------------
// Kernel 1: value = input_flatten @ W_val + b_val (bf16 MFMA), permuted store
// to (b, h, pos, d) bf16.  Block: 64 rows x 256 cols, 256 thr = 4 waves.
// Double-buffered LDS + register prefetch: ONE barrier per K-iteration,
// global-load latency overlapped with MFMA.
// ---------------------------------------------------------------------------
__global__ __launch_bounds__(256) void k_valproj(
    const float* __restrict__ A,             // (134400, 256) fp32
    const __hip_bfloat16* __restrict__ Wt,   // tiled bf16 W^T
    const float* __restrict__ bias,          // (256,)
    __hip_bfloat16* __restrict__ V)          // (16, 8, 8400, 32)
{
    __shared__ __hip_bfloat16 As[2][64 * KP];
    __shared__ __hip_bfloat16 Ws[2][256 * KP];

    const int t    = threadIdx.x;
    const int m0   = blockIdx.x * 64;
    const int wave = t >> 6;
    const int lane = t & 63;
    const int lm   = lane & 31;
    const int lk   = (lane >> 5) * 8;

    f32x16 acc[2][2];
#pragma unroll
    for (int i = 0; i < 2; i++)
#pragma unroll
        for (int j = 0; j < 2; j++)
#pragma unroll
            for (int e = 0; e < 16; e++) acc[i][j][e] = 0.f;

    const int ar = t >> 2;
    const int ak = (t & 3) * 8;

    float4 a0, a1;
    bf16x8 w0, w1, w2, w3;

    // prologue: load k-tile 0
    {
        const float* ap = A + (size_t)(m0 + ar) * 256 + ak;
        a0 = *(const float4*)ap;
        a1 = *(const float4*)(ap + 4);
        const __hip_bfloat16* wp = Wt + t * 32;
        w0 = *(const bf16x8*)(wp + 0);
        w1 = *(const bf16x8*)(wp + 8);
        w2 = *(const bf16x8*)(wp + 16);
        w3 = *(const bf16x8*)(wp + 24);
    }
    // stage into buf 0
    {
        union { __hip_bfloat162 h2[4]; bf16x8 v; } ua;
        ua.h2[0] = __float22bfloat162_rn(make_float2(a0.x, a0.y));
        ua.h2[1] = __float22bfloat162_rn(make_float2(a0.z, a0.w));
        ua.h2[2] = __float22bfloat162_rn(make_float2(a1.x, a1.y));
        ua.h2[3] = __float22bfloat162_rn(make_float2(a1.z, a1.w));
        *(bf16x8*)(&As[0][ar * KP + ak]) = ua.v;
        __hip_bfloat16* wd = &Ws[0][t * KP];
        *(bf16x8*)(wd + 0)  = w0;
        *(bf16x8*)(wd + 8)  = w1;
        *(bf16x8*)(wd + 16) = w2;
        *(bf16x8*)(wd + 24) = w3;
    }
    __syncthreads();

    for (int it = 0; it < 8; ++it) {
        float4 na0, na1;
        bf16x8 nw0, nw1, nw2, nw3;
        if (it < 7) {
            const int kt = (it + 1) * 32;
            const float* ap = A + (size_t)(m0 + ar) * 256 + kt + ak;
            na0 = *(const float4*)ap;
            na1 = *(const float4*)(ap + 4);
            const __hip_bfloat16* wp = Wt + (size_t)(it + 1) * 8192 + t * 32;
            nw0 = *(const bf16x8*)(wp + 0);
            nw1 = *(const bf16x8*)(wp + 8);
            nw2 = *(const bf16x8*)(wp + 16);
            nw3 = *(const bf16x8*)(wp + 24);
        }
        const int buf = it & 1;
#pragma unroll
        for (int kk = 0; kk < 32; kk += 16) {
            bf16x8 af0 = *(const bf16x8*)(&As[buf][(0 * 32 + lm) * KP + kk + lk]);
            bf16x8 af1 = *(const bf16x8*)(&As[buf][(1 * 32 + lm) * KP + kk + lk]);
            bf16x8 bf0 = *(const bf16x8*)(&Ws[buf][(wave * 64 + 0 * 32 + lm) * KP + kk + lk]);
            bf16x8 bf1 = *(const bf16x8*)(&Ws[buf][(wave * 64 + 1 * 32 + lm) * KP + kk + lk]);
            acc[0][0] = __builtin_amdgcn_mfma_f32_32x32x16_bf16(af0, bf0, acc[0][0], 0, 0, 0);
            acc[0][1] = __builtin_amdgcn_mfma_f32_32x32x16_bf16(af0, bf1, acc[0][1], 0, 0, 0);
            acc[1][0] = __builtin_amdgcn_mfma_f32_32x32x16_bf16(af1, bf0, acc[1][0], 0, 0, 0);
            acc[1][1] = __builtin_amdgcn_mfma_f32_32x32x16_bf16(af1, bf1, acc[1][1], 0, 0, 0);
        }
        if (it < 7) {
            union { __hip_bfloat162 h2[4]; bf16x8 v; } ua;
            ua.h2[0] = __float22bfloat162_rn(make_float2(na0.x, na0.y));
            ua.h2[1] = __float22bfloat162_rn(make_float2(na0.z, na0.w));
            ua.h2[2] = __float22bfloat162_rn(make_float2(na1.x, na1.y));
            ua.h2[3] = __float22bfloat162_rn(make_float2(na1.z, na1.w));
            const int nb = buf ^ 1;
            *(bf16x8*)(&As[nb][ar * KP + ak]) = ua.v;
            __hip_bfloat16* wd = &Ws[nb][t * KP];
            *(bf16x8*)(wd + 0)  = nw0;
            *(bf16x8*)(wd + 8)  = nw1;
            *(bf16x8*)(wd + 16) = nw2;
            *(bf16x8*)(wd + 24) = nw3;
            __syncthreads();
        }
    }

#pragma unroll
    for (int ni = 0; ni < 2; ni++) {
        const int n  = wave * 64 + ni * 32 + lm;
        const float bn = bias[n];
        const int h  = n >> 5;
        const int d  = n & 31;
#pragma unroll
        for (int mi = 0; mi < 2; mi++) {
#pragma unroll
            for (int r = 0; r < 16; r++) {
                int rl = (r & 3) + 8 * (r >> 2) + 4 * (lane >> 5);
                int m  = m0 + mi * 32 + rl;
                int b  = m / NT;
                int pos = m - b * NT;
                V[((size_t)(b * NH + h) * NT + pos) * HD + d] =
                    __float2bfloat16(acc[mi][ni][r] + bn);
            }
        }
    }
}

// ---------------------------------------------------------------------------
// Kernel 2 (MFMA): [off_raw | attn_raw] = query @ [W_off | W_attn] + bias.
// ---------------------------------------------------------------------------
__global__ __launch_bounds__(192) void k_offattn(
    const float* __restrict__ Q,             // (4800, 256)
    const __hip_bfloat16* __restrict__ Wt2,  // tiled bf16 [W_off|W_attn]^T
    const float* __restrict__ boff,          // (192,)
    const float* __restrict__ battn,         // (96,)
    float* __restrict__ off_out,             // (4800, 192)
    float* __restrict__ attn_out)            // (4800, 96)
{
    __shared__ __hip_bfloat16 As[32 * KP];
    __shared__ __hip_bfloat16 Ws[288 * KP];

    const int t    = threadIdx.x;
    const int m0   = blockIdx.x * 32;
    const int wave = t >> 6;       // 0..2
    const int lane = t & 63;
    const int lm   = lane & 31;
    const int lk   = (lane >> 5) * 8;

    f32x16 acc[3];
#pragma unroll
    for (int j = 0; j < 3; j++)
#pragma unroll
        for (int e = 0; e < 16; e++) acc[j][e] = 0.f;

    for (int kt = 0; kt < 256; kt += 32) {
        if (t < 128) {
            const int ar = t >> 2;
            const int ak = (t & 3) * 8;
            const float* ap = Q + (size_t)(m0 + ar) * 256 + kt + ak;
            float4 a0 = *(const float4*)ap;
            float4 a1 = *(const float4*)(ap + 4);
            union { __hip_bfloat162 h2[4]; bf16x8 v; } ua;
            ua.h2[0] = __float22bfloat162_rn(make_float2(a0.x, a0.y));
            ua.h2[1] = __float22bfloat162_rn(make_float2(a0.z, a0.w));
            ua.h2[2] = __float22bfloat162_rn(make_float2(a1.x, a1.y));
            ua.h2[3] = __float22bfloat162_rn(make_float2(a1.z, a1.w));
            *(bf16x8*)(As + ar * KP + ak) = ua.v;
        }
        {
            const __hip_bfloat16* wp = Wt2 + (size_t)(kt >> 5) * 9216 + t * 32;
            __hip_bfloat16* wd = Ws + t * KP;
            *(bf16x8*)(wd + 0)  = *(const bf16x8*)(wp + 0);
            *(bf16x8*)(wd + 8)  = *(const bf16x8*)(wp + 8);
            *(bf16x8*)(wd + 16) = *(const bf16x8*)(wp + 16);
            *(bf16x8*)(wd + 24) = *(const bf16x8*)(wp + 24);
            if (t < 96) {
                const __hip_bfloat16* wp2 = Wt2 + (size_t)(kt >> 5) * 9216 + (t + 192) * 32;
                __hip_bfloat16* wd2 = Ws + (t + 192) * KP;
                *(bf16x8*)(wd2 + 0)  = *(const bf16x8*)(wp2 + 0);
                *(bf16x8*)(wd2 + 8)  = *(const bf16x8*)(wp2 + 8);
                *(bf16x8*)(wd2 + 16) = *(const bf16x8*)(wp2 + 16);
                *(bf16x8*)(wd2 + 24) = *(const bf16x8*)(wp2 + 24);
            }
        }
        __syncthreads();

#pragma unroll
        for (int kk = 0; kk < 32; kk += 16) {
            bf16x8 af = *(const bf16x8*)(As + lm * KP + kk + lk);
#pragma unroll
            for (int j = 0; j < 3; j++) {
                bf16x8 bf = *(const bf16x8*)(Ws + (wave * 96 + j * 32 + lm) * KP + kk + lk);
                acc[j] = __builtin_amdgcn_mfma_f32_32x32x16_bf16(af, bf, acc[j], 0, 0, 0);
            }
        }
        __syncthreads();
    }

#pragma unroll
    for (int j = 0; j < 3; j++) {
        const int n = wave * 96 + j * 32 + lm;
        const float bias_ = (n < 192) ? boff[n] : battn[n - 192];
#pragma unroll
        for (int r = 0; r < 16; r++) {
            int rl = (r & 3) + 8 * (r >> 2) + 4 * (lane >> 5);
            int m  = m0 + rl;
            float v = acc[j][r] + bias_;
            if (n < 192) off_out[(size_t)m * 192 + n] = v;
            else         attn_out[(size_t)m * 96 + (n - 192)] = v;
        }
    }
}

// ---------------------------------------------------------------------------
// Kernel 3: softmax + sampling.  2 queries per block (256 thr = 2 x 128).
// Phase 1: per-point corner indices + attention-folded corner weights in LDS.
// Phase 2: thread = (query, head, channel-pair); bf16x2 gathers; bf16 output.
// ---------------------------------------------------------------------------
__global__ __launch_bounds__(256) void k_sample(
    const float* __restrict__ off_raw,   // (4800, 192)  (h,l,p,2)
    const float* __restrict__ attn_raw,  // (4800, 96)   (h, l*4+p)
    const float* __restrict__ refp,      // (16, 300, 3, 2)
    const __hip_bfloat16* __restrict__ V,// (16, 8, 8400, 32)
    __hip_bfloat16* __restrict__ sampled)// (4800, 256) bf16
{
    const int t  = threadIdx.x;
    const int q2 = t >> 7;          // 0..1
    const int tq = t & 127;
    const int bq = blockIdx.x * 2 + q2;
    const int b  = bq / LQ;

    __shared__ float aw[2][96];
    __shared__ float wc[2][96][4];
    __shared__ int   ic[2][96][4];

    // phase 1a: softmax per head
    if (tq < 8) {
        float v[12];
        float mx = -1e30f;
#pragma unroll
        for (int i = 0; i < 12; i++) {
            v[i] = attn_raw[(size_t)bq * 96 + tq * 12 + i];
            mx = fmaxf(mx, v[i]);
        }
        float s = 0.f;
#pragma unroll
        for (int i = 0; i < 12; i++) { v[i] = expf(v[i] - mx); s += v[i]; }
        float inv = 1.f / s;
#pragma unroll
        for (int i = 0; i < 12; i++) aw[q2][tq * 12 + i] = v[i] * inv;
    }
    __syncthreads();

    // phase 1b: per-point corner data
    if (tq < 96) {
        const float dims[3]  = {80.f, 40.f, 20.f};
        const int startsl[3] = {0, 6400, 8000};
        const int idiml[3]   = {80, 40, 20};
        int h = tq / 12, lp = tq - h * 12, l = lp >> 2, p = lp & 3;
        float ox = off_raw[(size_t)bq * 192 + ((h * 3 + l) * 4 + p) * 2 + 0];
        float oy = off_raw[(size_t)bq * 192 + ((h * 3 + l) * 4 + p) * 2 + 1];
        float rx = refp[(size_t)bq * 6 + l * 2 + 0];
        float ry = refp[(size_t)bq * 6 + l * 2 + 1];
        float D  = dims[l];
        float lx = rx + ox / D;
        float ly = ry + oy / D;
        float ix = lx * D - 0.5f;
        float iy = ly * D - 0.5f;
        const int Dl = idiml[l];
        const int st = startsl[l];

        float fix = floorf(ix), fiy = floorf(iy);
        int ix0 = (int)fix, iy0 = (int)fiy;
        int ix1 = ix0 + 1, iy1 = iy0 + 1;
        float fx = ix - fix, fy = iy - fiy;

        float mx0 = (ix0 >= 0 && ix0 < Dl) ? 1.f : 0.f;
        float mx1 = (ix1 >= 0 && ix1 < Dl) ? 1.f : 0.f;
        float my0 = (iy0 >= 0 && iy0 < Dl) ? 1.f : 0.f;
        float my1 = (iy1 >= 0 && iy1 < Dl) ? 1.f : 0.f;

        int cx0 = min(max(ix0, 0), Dl - 1);
        int cx1 = min(max(ix1, 0), Dl - 1);
        int cy0 = min(max(iy0, 0), Dl - 1);
        int cy1 = min(max(iy1, 0), Dl - 1);

        float a = aw[q2][tq];
        wc[q2][tq][0] = (1.f - fx) * (1.f - fy) * mx0 * my0 * a;
        wc[q2][tq][1] = fx * (1.f - fy) * mx1 * my0 * a;
        wc[q2][tq][2] = (1.f - fx) * fy * mx0 * my1 * a;
        wc[q2][tq][3] = fx * fy * mx1 * my1 * a;
        ic[q2][tq][0] = (st + cy0 * Dl + cx0) * HD;
        ic[q2][tq][1] = (st + cy0 * Dl + cx1) * HD;
        ic[q2][tq][2] = (st + cy1 * Dl + cx0) * HD;
        ic[q2][tq][3] = (st + cy1 * Dl + cx1) * HD;
    }
    __syncthreads();

    // phase 2: gather + weighted sum, 2 channels per thread
    const int h  = tq >> 4;
    const int dp = (tq & 15) * 2;
    const __hip_bfloat16* vb = V + (size_t)(b * NH + h) * NT * HD + dp;

    float acc0 = 0.f, acc1 = 0.f;
#pragma unroll
    for (int lp = 0; lp < 12; lp++) {
        const int s = h * 12 + lp;
        float4 w4 = *(const float4*)(&wc[q2][s][0]);
        int4   i4 = *(const int4*)(&ic[q2][s][0]);
        float2 v00 = __bfloat1622float2(*(const __hip_bfloat162*)(vb + i4.x));
        float2 v01 = __bfloat1622float2(*(const __hip_bfloat162*)(vb + i4.y));
        float2 v10 = __bfloat1622float2(*(const __hip_bfloat162*)(vb + i4.z));
        float2 v11 = __bfloat1622float2(*(const __hip_bfloat162*)(vb + i4.w));
        acc0 = fmaf(w4.x, v00.x, fmaf(w4.y, v01.x, fmaf(w4.z, v10.x, fmaf(w4.w, v11.x, acc0))));
        acc1 = fmaf(w4.x, v00.y, fmaf(w4.y, v01.y, fmaf(w4.z, v10.y, fmaf(w4.w, v11.y, acc1))));
    }
    *(__hip_bfloat162*)(sampled + (size_t)bq * 256 + h * 32 + dp) =
        __float22bfloat162_rn(make_float2(acc0, acc1));
}

// ---------------------------------------------------------------------------
// Kernel 4 (MFMA): out = sampled(bf16) @ W_out + b_out.
// Block: 32 rows x 256 cols, 256 thr = 4 waves; wave covers 64 n = 2 tiles.
// ---------------------------------------------------------------------------
__global__ __launch_bounds__(256) void k_outproj(
    const __hip_bfloat16* __restrict__ A,    // (4800, 256) bf16
    const __hip_bfloat16* __restrict__ Wt3,  // tiled bf16 W_out^T
    const float* __restrict__ bias,          // (256,)
    float* __restrict__ out)                 // (4800, 256)
{
    __shared__ __hip_bfloat16 As[32 * KP];
    __shared__ __hip_bfloat16 Ws[256 * KP];

    const int t    = threadIdx.x;
    const int m0   = blockIdx.x * 32;
    const int wave = t >> 6;       // 0..3
    const int lane = t & 63;
    const int lm   = lane & 31;
    const int lk   = (lane >> 5) * 8;

    f32x16 acc[2];
#pragma unroll
    for (int j = 0; j < 2; j++)
#pragma unroll
        for (int e = 0; e < 16; e++) acc[j][e] = 0.f;

    const int ar = t >> 3;         // 0..31
    const int ak = (t & 7) * 4;    // 0..28

    for (int kt = 0; kt < 256; kt += 32) {
        // stage A (32 x 32) bf16: thread loads bf16x4
        *(bf16x4*)(As + ar * KP + ak) =
            *(const bf16x4*)(A + (size_t)(m0 + ar) * 256 + kt + ak);
        // stage W (256 n x 32 k): thread t = row n
        {
            const __hip_bfloat16* wp = Wt3 + (size_t)(kt >> 5) * 8192 + t * 32;
            __hip_bfloat16* wd = Ws + t * KP;
            *(bf16x8*)(wd + 0)  = *(const bf16x8*)(wp + 0);
            *(bf16x8*)(wd + 8)  = *(const bf16x8*)(wp + 8);
            *(bf16x8*)(wd + 16) = *(const bf16x8*)(wp + 16);
            *(bf16x8*)(wd + 24) = *(const bf16x8*)(wp + 24);
        }
        __syncthreads();

#pragma unroll
        for (int kk = 0; kk < 32; kk += 16) {
            bf16x8 af = *(const bf16x8*)(As + lm * KP + kk + lk);
            bf16x8 bf0 = *(const bf16x8*)(Ws + (wave * 64 + 0 * 32 + lm) * KP + kk + lk);
            bf16x8 bf1 = *(const bf16x8*)(Ws + (wave * 64 + 1 * 32 + lm) * KP + kk + lk);
            acc[0] = __builtin_amdgcn_mfma_f32_32x32x16_bf16(af, bf0, acc[0], 0, 0, 0);
            acc[1] = __builtin_amdgcn_mfma_f32_32x32x16_bf16(af, bf1, acc[1], 0, 0, 0);
        }
        __syncthreads();
    }

#pragma unroll
    for (int j = 0; j < 2; j++) {
        const int n = wave * 64 + j * 32 + lm;
        const float bn = bias[n];
#pragma unroll
        for (int r = 0; r < 16; r++) {
            int rl = (r & 3) + 8 * (r >> 2) + 4 * (lane >> 5);
            int m  = m0 + rl;
            out[(size_t)m * 256 + n] = acc[j][r] + bn;
        }
    }
}

// ---------------------------------------------------------------------------
extern "C" void kernel_launch(void* const* d_in, const int* in_sizes, int n_in,
                              void* d_out, int out_size, void* d_ws, size_t ws_size,
                              hipStream_t stream) {
    const float* query  = (const float*)d_in[0];
    const float* refp   = (const float*)d_in[1];
    const float* inputf = (const float*)d_in[2];
    const float* W_off  = (const float*)d_in[3];
    const float* b_off  = (const float*)d_in[4];
    const float* W_attn = (const float*)d_in[5];
    const float* b_attn = (const float*)d_in[6];
    const float* W_val  = (const float*)d_in[7];
    const float* b_val  = (const float*)d_in[8];
    const float* W_out  = (const float*)d_in[9];
    const float* b_out  = (const float*)d_in[10];
    float* out = (float*)d_out;

    char* ws = (char*)d_ws;
    // layout (77,209,600 B total; ws proven >= 79.26 MB in round 1):
    __hip_bfloat16* value   = (__hip_bfloat16*)ws;                       // 68,812,800
    float* off_raw          = (float*)(ws + 68812800);                   //  3,686,400
    float* attn_raw         = (float*)(ws + 72499200);                   //  1,843,200
    __hip_bfloat16* sampled = (__hip_bfloat16*)(ws + 74342400);          //  2,457,600
    __hip_bfloat16* Wt      = (__hip_bfloat16*)(ws + 76800000);          //    131,072
    __hip_bfloat16* Wt2     = (__hip_bfloat16*)(ws + 76931072);          //    147,456
    __hip_bfloat16* Wt3     = (__hip_bfloat16*)(ws + 77078528);          //    131,072

    k_wt<<<800, 256, 0, stream>>>(W_val, W_off, W_attn, W_out, Wt, Wt2, Wt3);
    k_valproj<<<MROWS / 64, 256, 0, stream>>>(inputf, Wt, b_val, value);
    k_offattn<<<QROWS / 32, 192, 0, stream>>>(query, Wt2, b_off, b_attn,
                                              off_raw, attn_raw);
    k_sample<<<QROWS / 2, 256, 0, stream>>>(off_raw, attn_raw, refp, value, sampled);
    k_outproj<<<QROWS / 32, 256, 0, stream>>>(sampled, Wt3, b_out, out);
}